// Round 7
// baseline (334.272 us; speedup 1.0000x reference)
//
#include <hip/hip_runtime.h>
#include <hip/hip_bf16.h>
#include <stdint.h>

// B=524288, H=64, D=1. fp32 in/out.
// R8b: byte-equivalent resubmission of R8 ("container failed twice" — same
// infra false-negative signature as R6, whose unchanged resubmission R6b ran
// fine; R8 re-audited: no OOB, no hang path, single uniform barrier).
// R8 = R7 (104us, proven clean) + occupancy attack. Diagnosis chain:
//  - R7: cut VALU work -> wall flat  => not VALU-throughput-bound
//  - R5: halved LDS reads -> wall worse => not LDS-throughput-bound
//  - MFMA 13%, HBM 17% => neither
//  => latency-bound at 12 waves/CU, capped by 68KB LDS (2 blocks/CU).
// Fix: stage only K-slices s=0..2 of Wc in LDS (48 KB; total ~50.4 KB ->
// 3 blocks/CU = 24 waves). The s=3 slice (16 KB, shared by all blocks) is
// read per-phase via coalesced 16B/lane global loads -> L1-resident,
// consumed by the LAST MFMA of each 4-chain (max cover).
// __launch_bounds__(512,6) = exactly 3 blocks/CU, VGPR cap 85 (no 64-cap
// spill cliff: R4/R6b lesson applies to 1024-thr blocks only).

typedef __attribute__((ext_vector_type(8))) __bf16  bf16x8;
typedef __attribute__((ext_vector_type(8))) float   f32x8;
typedef __attribute__((ext_vector_type(4))) float   floatx4;

__device__ __forceinline__ unsigned short f2bf_bits(float x){
    unsigned u = __builtin_bit_cast(unsigned, x);
    u = u + 0x7fffu + ((u >> 16) & 1u);          // RNE
    return (unsigned short)(u >> 16);
}
__device__ __forceinline__ bf16x8 pack8(float4 a, float4 b){
    f32x8 t;
    t[0]=a.x; t[1]=a.y; t[2]=a.z; t[3]=a.w;
    t[4]=b.x; t[5]=b.y; t[6]=b.z; t[7]=b.w;
    return __builtin_convertvector(t, bf16x8);   // v_cvt_pk_bf16_f32, RNE
}

// ---------------------------------------------------------------------------
// Prep (unchanged, proven correct): Wc[256x128] bf16 in MFMA-B fragment
// order; biasc[n] = b_ih+b_hh+W_ih@b2 (raw; prescaling happens at staging).
// ---------------------------------------------------------------------------
__global__ __launch_bounds__(256) void prep_kernel(
    const float* __restrict__ W2, const float* __restrict__ b2,
    const float* __restrict__ W_ih, const float* __restrict__ W_hh,
    const float* __restrict__ b_ih, const float* __restrict__ b_hh,
    unsigned short* __restrict__ wc, float* __restrict__ biasc)
{
    __shared__ float W2s[64*64];
    __shared__ float b2s[64];
    __shared__ float wihs[16*64];
    const int tid = threadIdx.x;
    const int b   = blockIdx.x;          // 0..15

    for (int i = 0; i < 4; i++){
        int idx = i*1024 + tid*4;
        *(float4*)(W2s + idx) = *(const float4*)(W2 + idx);
    }
    if (tid < 64) b2s[tid] = b2[tid];
    {
        int idx = tid*4;
        *(float4*)(wihs + idx) = *(const float4*)(W_ih + b*16*64 + idx);
    }
    __syncthreads();

    const int nl = tid >> 4;
    const int n  = b*16 + nl;
    const int jg = tid & 15;
    const int j  = jg*4;
    const int T  = n >> 4;

    float a0=0.f, a1=0.f, a2=0.f, a3=0.f;
    for (int h = 0; h < 64; h++){
        float wv = wihs[nl*64 + h];
        const float* w2r = W2s + h*64 + j;
        a0 += wv*w2r[0]; a1 += wv*w2r[1]; a2 += wv*w2r[2]; a3 += wv*w2r[3];
    }
    auto store4 = [&](int k, float v0, float v1, float v2, float v3){
        int s    = k >> 5;
        int lane = ((k >> 3) & 3)*16 + (n & 15);
        int off  = (T*4 + s)*512 + lane*8 + (k & 7);
        ushort4 v; v.x=f2bf_bits(v0); v.y=f2bf_bits(v1); v.z=f2bf_bits(v2); v.w=f2bf_bits(v3);
        *(ushort4*)(wc + off) = v;
    };
    store4(j, a0, a1, a2, a3);
    {
        const float* src = W_hh + n*64 + j;
        store4(64 + j, src[0], src[1], src[2], src[3]);
    }
    if (jg == 0){
        float s = b_ih[n] + b_hh[n];
        for (int h = 0; h < 64; h++) s += wihs[nl*64 + h]*b2s[h];
        biasc[n] = s;
    }
}

// ---------------------------------------------------------------------------
// Main: 512 threads = 8 waves, 128 rows/block, 4096 blocks, 3 blocks/CU.
// Wave w: rows [row0+16w, row0+16w+16), all 256 gate cols, jh-grouped.
// ---------------------------------------------------------------------------
__global__ __launch_bounds__(512, 6) void main_kernel(
    const float* __restrict__ grad, const float* __restrict__ param,
    const float* __restrict__ mom,  const float* __restrict__ h0,
    const float* __restrict__ c0,   const float* __restrict__ W1,
    const float* __restrict__ b1,   const float* __restrict__ Wout,
    const float* __restrict__ bout,
    const unsigned short* __restrict__ wc, const float* __restrict__ biasc,
    float* __restrict__ out)
{
    __shared__ __align__(16) unsigned short wc_l[24576];  // 48 KB: s=0..2 per tile
    __shared__ float  bias_l[256];   // prescaled: -log2e*b (i,f,o), +2log2e*b (g)
    __shared__ float4 w1p_l[64];     // {W1[j][0..2], b1[j]}
    __shared__ float  wout_l[64];

    const int tid  = threadIdx.x;
    const int lane = tid & 63;
    const int w    = tid >> 6;       // 0..7
    const int l15  = lane & 15;
    const int q    = lane >> 4;
    const long row0 = (long)blockIdx.x * 128;

    // ---- stage Wc slices s=0..2 + tables into LDS (single barrier) ----
    // global float4 idx (T*4+s)*64+u  ->  LDS float4 idx (T*3+s)*64+u (linear d)
    {
        const float4* src = (const float4*)wc;
        float4*       dst = (float4*)wc_l;
        #pragma unroll
        for (int i = 0; i < 6; i++){
            int d   = i*512 + tid;        // 0..3071
            int T   = d / 192;            // 0..15
            int rem = d - T*192;          // s*64+u, s in 0..2
            dst[d] = src[T*256 + rem];
        }
    }
    if (tid < 256){
        float sc = ((tid >> 6) == 2) ? 2.885390082f : -1.442695041f;
        bias_l[tid] = sc * biasc[tid];
    } else if (tid < 320){
        int j = tid - 256;
        w1p_l[j] = make_float4(W1[j*3], W1[j*3+1], W1[j*3+2], b1[j]);
    } else if (tid < 384){
        wout_l[tid - 320] = Wout[tid - 320];
    }

    // ---- per-lane A-row input loads (issued under staging) ----
    const long rA = row0 + w*16 + l15;          // this lane's A row
    float g = grad[rA], p = param[rA], mo = mom[rA];
    const float* hrow = h0 + rA*64;
    float4 ha = *(const float4*)(hrow + q*8);
    float4 hb = *(const float4*)(hrow + q*8 + 4);
    float4 hc = *(const float4*)(hrow + 32 + q*8);
    float4 hd = *(const float4*)(hrow + 32 + q*8 + 4);
    const float bout0 = bout[0];

    __syncthreads();   // wc_l / bias_l / w1p_l / wout_l ready

    // ---- A-fragment build (r part from the tiny MLP, h0 part packed) ----
    float m = fmaf(0.9f, mo, g);
    f32x8 rlo, rhi;
    #pragma unroll
    for (int jj = 0; jj < 8; jj++){
        float4 wr = w1p_l[q*8 + jj];
        float v = fmaf(wr.x, g, fmaf(wr.y, p, fmaf(wr.z, m, wr.w)));
        rlo[jj] = v > 0.f ? v : 0.f;
    }
    #pragma unroll
    for (int jj = 0; jj < 8; jj++){
        float4 wr = w1p_l[32 + q*8 + jj];
        float v = fmaf(wr.x, g, fmaf(wr.y, p, fmaf(wr.z, m, wr.w)));
        rhi[jj] = v > 0.f ? v : 0.f;
    }
    bf16x8 afr0 = __builtin_convertvector(rlo, bf16x8);
    bf16x8 afr1 = __builtin_convertvector(rhi, bf16x8);
    bf16x8 afr2 = pack8(ha, hb);
    bf16x8 afr3 = pack8(hc, hd);

    // ---- c0 depth-2 pipeline: groups 0,1 issued here; jh+2 at top of jh ----
    const float* c0b = c0 + (rA & ~15L)*64 + (q*4)*64 + l15;  // rows w*16+q*4.., col l15
    float c0v0[4], c0v1[4], c0v2[4], c0v3[4];
    #pragma unroll
    for (int r = 0; r < 4; ++r) c0v0[r] = c0b[r*64];
    #pragma unroll
    for (int r = 0; r < 4; ++r) c0v1[r] = c0b[r*64 + 16];

    float red[4] = {0.f, 0.f, 0.f, 0.f};
    const floatx4 zq = {0.f, 0.f, 0.f, 0.f};

// tile T: s=0..2 from LDS at (T*3+s)*512 ushorts; s=3 passed in (global/L1)
#define GATE1(T, d, S3)                                                       \
{                                                                             \
    const unsigned short* pp = wc_l + (T)*1536 + lane*8;                      \
    bf16x8 t0 = *(const bf16x8*)(pp);                                         \
    bf16x8 t1 = *(const bf16x8*)(pp + 512);                                   \
    bf16x8 t2 = *(const bf16x8*)(pp + 1024);                                  \
    d = __builtin_amdgcn_mfma_f32_16x16x32_bf16(afr0, t0, zq, 0,0,0);         \
    d = __builtin_amdgcn_mfma_f32_16x16x32_bf16(afr1, t1, d,  0,0,0);         \
    d = __builtin_amdgcn_mfma_f32_16x16x32_bf16(afr2, t2, d,  0,0,0);         \
    d = __builtin_amdgcn_mfma_f32_16x16x32_bf16(afr3, S3, d,  0,0,0);         \
}

#define EPILOG(XI, XF, XG, XO, CV, BI, BF, BG, BO, WO)                        \
    _Pragma("unroll")                                                         \
    for (int r = 0; r < 4; ++r){                                              \
        float ei = __builtin_amdgcn_exp2f(fmaf(-1.442695041f, XI[r], BI));    \
        float iv = __builtin_amdgcn_rcpf(1.0f + ei);                          \
        float ef = __builtin_amdgcn_exp2f(fmaf(-1.442695041f, XF[r], BF));    \
        float fv = __builtin_amdgcn_rcpf(1.0f + ef);                          \
        float eo = __builtin_amdgcn_exp2f(fmaf(-1.442695041f, XO[r], BO));    \
        float ov = __builtin_amdgcn_rcpf(1.0f + eo);                          \
        float eg = __builtin_amdgcn_exp2f(fmaf( 2.885390082f, XG[r], BG));    \
        float gv = fmaf(-2.0f, __builtin_amdgcn_rcpf(1.0f + eg), 1.0f);       \
        float c1 = fmaf(fv, CV[r], iv*gv);                                    \
        float ec = __builtin_amdgcn_exp2f(2.885390082f * c1);                 \
        float tv = fmaf(-2.0f, __builtin_amdgcn_rcpf(1.0f + ec), 1.0f);       \
        red[r] = fmaf(ov * tv, WO, red[r]);                                   \
    }

#define PHASE(JH, CV, PRE_CV, DO_PRE)                                         \
{                                                                             \
    /* s=3 fragments for the 4 gate tiles: global, L1-hot, 16B coalesced */   \
    bf16x8 s3i = *(const bf16x8*)(wc + (((JH)     )*4+3)*512 + lane*8);       \
    bf16x8 s3f = *(const bf16x8*)(wc + (((JH) +  4)*4+3)*512 + lane*8);       \
    bf16x8 s3g = *(const bf16x8*)(wc + (((JH) +  8)*4+3)*512 + lane*8);       \
    bf16x8 s3o = *(const bf16x8*)(wc + (((JH) + 12)*4+3)*512 + lane*8);       \
    if (DO_PRE){                                                              \
        _Pragma("unroll")                                                     \
        for (int r = 0; r < 4; ++r) PRE_CV[r] = c0b[r*64 + ((JH)+2)*16];      \
    }                                                                         \
    const int jh16 = (JH) << 4;                                               \
    const float bsi = bias_l[jh16 + l15];                                     \
    const float bsf = bias_l[jh16 + l15 + 64];                                \
    const float bsg = bias_l[jh16 + l15 + 128];                               \
    const float bso = bias_l[jh16 + l15 + 192];                               \
    const float wo  = wout_l[jh16 + l15];                                     \
    floatx4 xi, xf, xg, xo;                                                   \
    GATE1((JH),      xi, s3i)                                                 \
    GATE1((JH) + 4,  xf, s3f)                                                 \
    GATE1((JH) + 8,  xg, s3g)                                                 \
    GATE1((JH) + 12, xo, s3o)                                                 \
    EPILOG(xi, xf, xg, xo, CV, bsi, bsf, bsg, bso, wo)                        \
}

    PHASE(0, c0v0, c0v2, 1)
    PHASE(1, c0v1, c0v3, 1)
    PHASE(2, c0v2, c0v0, 0)
    PHASE(3, c0v3, c0v0, 0)

#undef PHASE
#undef EPILOG
#undef GATE1

    // ---- reduce over l15 (16-lane butterfly), store ----
    #pragma unroll
    for (int mset = 1; mset < 16; mset <<= 1)
        #pragma unroll
        for (int r = 0; r < 4; r++)
            red[r] += __shfl_xor(red[r], mset, 64);

    if (l15 == 0){
        long orow = row0 + w*16 + q*4;
        #pragma unroll
        for (int r = 0; r < 4; r++)
            out[orow + r] = red[r] + bout0;
    }
}

extern "C" void kernel_launch(void* const* d_in, const int* in_sizes, int n_in,
                              void* d_out, int out_size, void* d_ws, size_t ws_size,
                              hipStream_t stream)
{
    const float* grad  = (const float*)d_in[0];
    const float* param = (const float*)d_in[1];
    const float* mom   = (const float*)d_in[2];
    const float* h0    = (const float*)d_in[3];
    const float* c0    = (const float*)d_in[4];
    const float* W1    = (const float*)d_in[5];
    const float* b1    = (const float*)d_in[6];
    const float* W2    = (const float*)d_in[7];
    const float* b2    = (const float*)d_in[8];
    const float* W_ih  = (const float*)d_in[9];
    const float* W_hh  = (const float*)d_in[10];
    const float* b_ih  = (const float*)d_in[11];
    const float* b_hh  = (const float*)d_in[12];
    const float* Wout  = (const float*)d_in[13];
    const float* bout  = (const float*)d_in[14];

    unsigned short* wc = (unsigned short*)d_ws;
    float* biasc       = (float*)((char*)d_ws + 65536);

    prep_kernel<<<16, 256, 0, stream>>>(W2, b2, W_ih, W_hh, b_ih, b_hh, wc, biasc);

    const int nblocks = 524288 / 128;   // 4096
    main_kernel<<<nblocks, 512, 0, stream>>>(grad, param, mom, h0, c0,
                                             W1, b1, Wout, bout, wc, biasc,
                                             (float*)d_out);
}